// Round 12
// baseline (225.214 us; speedup 1.0000x reference)
//
#include <hip/hip_runtime.h>
#include <hip/hip_bf16.h>

// Problem constants
#define Bsz 4
#define SEQ 1024
#define DIM 512
#define HEADS 8
#define DIM_HEAD 64
#define ROWS (Bsz * SEQ)        // 4096
#define QKV3 (3 * DIM_HEAD)     // 192

typedef _Float16 f16x4 __attribute__((ext_vector_type(4)));
typedef float f32x4 __attribute__((ext_vector_type(4)));

// ---------------------------------------------------------------------------
// LayerNorm: one block per row of x [ROWS, 512]  (unchanged)
// ---------------------------------------------------------------------------
__global__ __launch_bounds__(256) void ln_kernel(
    const float* __restrict__ x, const float* __restrict__ g,
    const float* __restrict__ beta, float* __restrict__ xn)
{
    int r = blockIdx.x;
    int t = threadIdx.x;
    const float* xr = x + (size_t)r * DIM;
    float v0 = xr[t], v1 = xr[t + 256];
    float s = v0 + v1, ss = v0 * v0 + v1 * v1;
    #pragma unroll
    for (int off = 32; off; off >>= 1) {
        s  += __shfl_xor(s, off);
        ss += __shfl_xor(ss, off);
    }
    __shared__ float rs[4], rss[4];
    int wave = t >> 6, lane = t & 63;
    if (lane == 0) { rs[wave] = s; rss[wave] = ss; }
    __syncthreads();
    s  = rs[0] + rs[1] + rs[2] + rs[3];
    ss = rss[0] + rss[1] + rss[2] + rss[3];
    float mu  = s * (1.0f / DIM);
    float var = ss * (1.0f / DIM) - mu * mu;
    float rstd = rsqrtf(var + 1e-5f);
    float* out = xn + (size_t)r * DIM;
    out[t]       = (v0 - mu) * rstd * g[t]       + beta[t];
    out[t + 256] = (v1 - mu) * rstd * g[t + 256] + beta[t + 256];
}

// ---------------------------------------------------------------------------
// fp16-MFMA GEMM, 64x64 tile (round-7 proven) — used for qkv (N=192)
// ---------------------------------------------------------------------------
template <int TRANS_B>
__global__ __launch_bounds__(256) void gemm16_kernel(
    const float* __restrict__ A, const float* __restrict__ B,
    float* __restrict__ C, const float* __restrict__ bias,
    int K, int lda, int ldb, int ldc,
    long strideA, long strideB, long strideC, float alpha)
{
    int bz = blockIdx.z;
    A += (size_t)bz * strideA;
    B += (size_t)bz * strideB;
    C += (size_t)bz * strideC;

    __shared__ _Float16 As[64][36];
    __shared__ _Float16 Bs[64][36];

    int t = threadIdx.x;
    int block_m = blockIdx.y * 64;
    int block_n = blockIdx.x * 64;
    int wave = t >> 6, lane = t & 63;
    int wm = wave >> 1, wn = wave & 1;
    int lrow = lane & 15, g = lane >> 4;

    int sm = t & 63;
    int kc = t >> 6;

    f32x4 acc[2][2] = {};

    for (int k0 = 0; k0 < K; k0 += 32) {
        {
            const float4* pa = reinterpret_cast<const float4*>(
                A + (size_t)(block_m + sm) * lda + k0 + kc * 8);
            float4 a0 = pa[0], a1 = pa[1];
            f16x4 h0 = { (_Float16)a0.x, (_Float16)a0.y, (_Float16)a0.z, (_Float16)a0.w };
            f16x4 h1 = { (_Float16)a1.x, (_Float16)a1.y, (_Float16)a1.z, (_Float16)a1.w };
            *(f16x4*)&As[sm][kc * 8]     = h0;
            *(f16x4*)&As[sm][kc * 8 + 4] = h1;
        }
        if (TRANS_B) {
            const float4* pb = reinterpret_cast<const float4*>(
                B + (size_t)(block_n + sm) * ldb + k0 + kc * 8);
            float4 b0 = pb[0], b1 = pb[1];
            f16x4 h0 = { (_Float16)b0.x, (_Float16)b0.y, (_Float16)b0.z, (_Float16)b0.w };
            f16x4 h1 = { (_Float16)b1.x, (_Float16)b1.y, (_Float16)b1.z, (_Float16)b1.w };
            *(f16x4*)&Bs[sm][kc * 8]     = h0;
            *(f16x4*)&Bs[sm][kc * 8 + 4] = h1;
        } else {
            const float* pb = B + (size_t)(k0 + kc * 8) * ldb + block_n + sm;
            float b[8];
            #pragma unroll
            for (int i = 0; i < 8; ++i) b[i] = pb[(size_t)i * ldb];
            f16x4 h0 = { (_Float16)b[0], (_Float16)b[1], (_Float16)b[2], (_Float16)b[3] };
            f16x4 h1 = { (_Float16)b[4], (_Float16)b[5], (_Float16)b[6], (_Float16)b[7] };
            *(f16x4*)&Bs[sm][kc * 8]     = h0;
            *(f16x4*)&Bs[sm][kc * 8 + 4] = h1;
        }
        __syncthreads();
        #pragma unroll
        for (int ks = 0; ks < 2; ++ks) {
            f16x4 a0 = *(const f16x4*)&As[32 * wm + lrow][ks * 16 + g * 4];
            f16x4 a1 = *(const f16x4*)&As[32 * wm + 16 + lrow][ks * 16 + g * 4];
            f16x4 b0 = *(const f16x4*)&Bs[32 * wn + lrow][ks * 16 + g * 4];
            f16x4 b1 = *(const f16x4*)&Bs[32 * wn + 16 + lrow][ks * 16 + g * 4];
            acc[0][0] = __builtin_amdgcn_mfma_f32_16x16x16f16(a0, b0, acc[0][0], 0, 0, 0);
            acc[0][1] = __builtin_amdgcn_mfma_f32_16x16x16f16(a0, b1, acc[0][1], 0, 0, 0);
            acc[1][0] = __builtin_amdgcn_mfma_f32_16x16x16f16(a1, b0, acc[1][0], 0, 0, 0);
            acc[1][1] = __builtin_amdgcn_mfma_f32_16x16x16f16(a1, b1, acc[1][1], 0, 0, 0);
        }
        __syncthreads();
    }

    #pragma unroll
    for (int mt = 0; mt < 2; ++mt)
        #pragma unroll
        for (int nt = 0; nt < 2; ++nt) {
            int n = block_n + 32 * wn + 16 * nt + lrow;
            float bv = bias ? bias[n] : 0.0f;
            #pragma unroll
            for (int i = 0; i < 4; ++i) {
                int m = block_m + 32 * wm + 16 * mt + g * 4 + i;
                C[(size_t)m * ldc + n] = acc[mt][nt][i] * alpha + bv;
            }
        }
}

// ---------------------------------------------------------------------------
// fp16-MFMA GEMM, 128x128 tile, 512 threads = 8 waves (2 wm x 4 wn).
// Wave tile 64x32 = 4x2 of 16x16 -> per ks: 6 b64 frag reads feed 8 MFMA
// (2.7x better LDS:MFMA ratio than the 64-tile kernel); staging amortized
// over 4x output. Same fragment mapping & k-order as gemm16_kernel.
// Used for dots (M=N=1024) and out (M=4096, N=512).
// ---------------------------------------------------------------------------
template <int TRANS_B>
__global__ __launch_bounds__(512) void gemm16_big(
    const float* __restrict__ A, const float* __restrict__ B,
    float* __restrict__ C, const float* __restrict__ bias,
    int K, int lda, int ldb, int ldc,
    long strideA, long strideB, long strideC, float alpha)
{
    int bz = blockIdx.z;
    A += (size_t)bz * strideA;
    B += (size_t)bz * strideB;
    C += (size_t)bz * strideC;

    __shared__ _Float16 As[128][36];   // 9 KB
    __shared__ _Float16 Bs[128][36];   // 9 KB

    int t = threadIdx.x;
    int block_m = blockIdx.y * 128;
    int block_n = blockIdx.x * 128;
    int wave = t >> 6, lane = t & 63;
    int wm = wave >> 2, wn = wave & 3;      // 2 x 4
    int lrow = lane & 15, g = lane >> 4;

    int sm = t & 127;   // staging row (m or n)
    int kc = t >> 7;    // 0..3: k-chunk of 8

    f32x4 acc[4][2] = {};

    for (int k0 = 0; k0 < K; k0 += 32) {
        { // A tile: 128 rows x 32 k
            const float4* pa = reinterpret_cast<const float4*>(
                A + (size_t)(block_m + sm) * lda + k0 + kc * 8);
            float4 a0 = pa[0], a1 = pa[1];
            f16x4 h0 = { (_Float16)a0.x, (_Float16)a0.y, (_Float16)a0.z, (_Float16)a0.w };
            f16x4 h1 = { (_Float16)a1.x, (_Float16)a1.y, (_Float16)a1.z, (_Float16)a1.w };
            *(f16x4*)&As[sm][kc * 8]     = h0;
            *(f16x4*)&As[sm][kc * 8 + 4] = h1;
        }
        if (TRANS_B) { // B[n][k] row-major
            const float4* pb = reinterpret_cast<const float4*>(
                B + (size_t)(block_n + sm) * ldb + k0 + kc * 8);
            float4 b0 = pb[0], b1 = pb[1];
            f16x4 h0 = { (_Float16)b0.x, (_Float16)b0.y, (_Float16)b0.z, (_Float16)b0.w };
            f16x4 h1 = { (_Float16)b1.x, (_Float16)b1.y, (_Float16)b1.z, (_Float16)b1.w };
            *(f16x4*)&Bs[sm][kc * 8]     = h0;
            *(f16x4*)&Bs[sm][kc * 8 + 4] = h1;
        } else {       // B[k][n] row-major: 8 per-k coalesced-across-lanes loads
            const float* pb = B + (size_t)(k0 + kc * 8) * ldb + block_n + sm;
            float b[8];
            #pragma unroll
            for (int i = 0; i < 8; ++i) b[i] = pb[(size_t)i * ldb];
            f16x4 h0 = { (_Float16)b[0], (_Float16)b[1], (_Float16)b[2], (_Float16)b[3] };
            f16x4 h1 = { (_Float16)b[4], (_Float16)b[5], (_Float16)b[6], (_Float16)b[7] };
            *(f16x4*)&Bs[sm][kc * 8]     = h0;
            *(f16x4*)&Bs[sm][kc * 8 + 4] = h1;
        }
        __syncthreads();
        #pragma unroll
        for (int ks = 0; ks < 2; ++ks) {
            f16x4 a[4], bb[2];
            #pragma unroll
            for (int mt = 0; mt < 4; ++mt)
                a[mt] = *(const f16x4*)&As[64 * wm + 16 * mt + lrow][ks * 16 + g * 4];
            #pragma unroll
            for (int nt = 0; nt < 2; ++nt)
                bb[nt] = *(const f16x4*)&Bs[32 * wn + 16 * nt + lrow][ks * 16 + g * 4];
            #pragma unroll
            for (int mt = 0; mt < 4; ++mt)
                #pragma unroll
                for (int nt = 0; nt < 2; ++nt)
                    acc[mt][nt] = __builtin_amdgcn_mfma_f32_16x16x16f16(
                        a[mt], bb[nt], acc[mt][nt], 0, 0, 0);
        }
        __syncthreads();
    }

    #pragma unroll
    for (int mt = 0; mt < 4; ++mt)
        #pragma unroll
        for (int nt = 0; nt < 2; ++nt) {
            int n = block_n + 32 * wn + 16 * nt + lrow;
            float bv = bias ? bias[n] : 0.0f;
            #pragma unroll
            for (int i = 0; i < 4; ++i) {
                int m = block_m + 64 * wm + 16 * mt + g * 4 + i;
                C[(size_t)m * ldc + n] = acc[mt][nt][i] * alpha + bv;
            }
        }
}

// ---------------------------------------------------------------------------
// FUSED LML solve + PV (unchanged from round 10).
// ---------------------------------------------------------------------------
__global__ __launch_bounds__(256) void solve_pv_kernel(
    const float* __restrict__ dots, const float* __restrict__ qkv,
    float* __restrict__ y)
{
    int r = blockIdx.x;
    int b = r >> 10;
    int t = threadIdx.x;
    int wave = t >> 6, lane = t & 63;
    int nbase = wave * 2;            // this wave solves N = nbase+1, nbase+2

    __shared__ float p_lds[8][1024];  // 32 KB; first 8 KB reused as ow later

    const float* x = dots + (size_t)r * SEQ;

    float e[16];
    #pragma unroll
    for (int s = 0; s < 4; ++s) {
        float4 v = *(const float4*)(x + lane * 4 + 256 * s);
        e[4 * s + 0] = v.x; e[4 * s + 1] = v.y;
        e[4 * s + 2] = v.z; e[4 * s + 3] = v.w;
    }
    float mx = e[0], mn = e[0];
    #pragma unroll
    for (int s = 1; s < 16; ++s) { mx = fmaxf(mx, e[s]); mn = fminf(mn, e[s]); }
    #pragma unroll
    for (int off = 32; off; off >>= 1) {
        mx = fmaxf(mx, __shfl_xor(mx, off));
        mn = fminf(mn, __shfl_xor(mn, off));
    }
    #pragma unroll
    for (int s = 0; s < 16; ++s) e[s] = __expf(e[s]);

    // E1..E4 = sums of e^x, e^2x, e^3x, e^4x (for the series init)
    float E1 = 0, E2 = 0, E3 = 0, E4 = 0;
    #pragma unroll
    for (int s = 0; s < 16; ++s) {
        float u = e[s], u2 = u * u;
        E1 += u; E2 += u2; E3 += u2 * u; E4 += u2 * u2;
    }
    #pragma unroll
    for (int off = 32; off; off >>= 1) {
        E1 += __shfl_xor(E1, off); E2 += __shfl_xor(E2, off);
        E3 += __shfl_xor(E3, off); E4 += __shfl_xor(E4, off);
    }

    float lo[2], hi[2], Nf[2], nu[2];
    #pragma unroll
    for (int k = 0; k < 2; ++k) {
        int N = nbase + k + 1;
        Nf[k] = (float)N;
        float lgt = __logf((float)N / (float)(SEQ - N));
        lo[k] = lgt - mx;             // provable bracket
        hi[k] = lgt - mn;
        // scalar Newton on the quartic series in t = e^nu
        float t0 = Nf[k] * __builtin_amdgcn_rcpf(E1);
        float tt = t0;
        #pragma unroll
        for (int it = 0; it < 4; ++it) {
            float gg = tt * (E1 + tt * (-E2 + tt * (E3 - tt * E4))) - Nf[k];
            float gp = E1 + tt * (-2.0f * E2 + tt * (3.0f * E3 - 4.0f * E4 * tt));
            float tn = tt - gg * __builtin_amdgcn_rcpf(gp);
            tt = (tn > 0.0f && tn < 1.0f) ? tn : t0;
        }
        float v = __logf(tt);
        nu[k] = (v > lo[k] && v < hi[k]) ? v : 0.5f * (lo[k] + hi[k]);
    }

    // ---- 4 bracket-guarded full Newton evals (inclusive-bound guard) ----
    for (int it = 0; it < 4; ++it) {
        float S[2], Sp[2];
        #pragma unroll
        for (int k = 0; k < 2; ++k) {
            float tn = __expf(nu[k]);
            float sn = 0.0f, spn = 0.0f;
            #pragma unroll
            for (int s = 0; s < 8; ++s) {
                float u1 = e[2 * s] * tn, u2 = e[2 * s + 1] * tn;
                float a1 = 1.0f + u1, a2 = 1.0f + u2;
                float rr = __builtin_amdgcn_rcpf(a1 * a2);
                float inv1 = rr * a2, inv2 = rr * a1;     // = 1/a1, 1/a2
                float p1 = u1 * inv1, p2 = u2 * inv2;
                sn += p1 + p2;
                spn = fmaf(p1, inv1, spn);                // p(1-p) = p*inv
                spn = fmaf(p2, inv2, spn);
            }
            S[k] = sn; Sp[k] = spn;
        }
        #pragma unroll
        for (int k = 0; k < 2; ++k) {
            #pragma unroll
            for (int off = 32; off; off >>= 1) {
                S[k]  += __shfl_xor(S[k], off);
                Sp[k] += __shfl_xor(Sp[k], off);
            }
            if (S[k] < Nf[k]) lo[k] = nu[k]; else hi[k] = nu[k];
            float step = (Nf[k] - S[k]) * __builtin_amdgcn_rcpf(Sp[k]);
            float cand = nu[k] + step;
            if (!(cand >= lo[k] && cand <= hi[k])) cand = 0.5f * (lo[k] + hi[k]);
            nu[k] = cand;
        }
    }

    // ---- write p for this wave's 2 nus from register e[] ----
    #pragma unroll
    for (int k = 0; k < 2; ++k) {
        float tn = __expf(nu[k]);
        #pragma unroll
        for (int s = 0; s < 4; ++s) {
            float u0 = e[4 * s + 0] * tn, u1 = e[4 * s + 1] * tn;
            float u2 = e[4 * s + 2] * tn, u3 = e[4 * s + 3] * tn;
            float4 pp;
            pp.x = u0 * __builtin_amdgcn_rcpf(1.0f + u0);
            pp.y = u1 * __builtin_amdgcn_rcpf(1.0f + u1);
            pp.z = u2 * __builtin_amdgcn_rcpf(1.0f + u2);
            pp.w = u3 * __builtin_amdgcn_rcpf(1.0f + u3);
            *(float4*)&p_lds[nbase + k][lane * 4 + 256 * s] = pp;
        }
    }
    __syncthreads();

    // ---- PV: wave w covers j in [256w, 256w+256); lane = (q, d4) ----
    int q = lane >> 4;          // j = jbase + 4*jj + q
    int dgrp = lane & 15;       // d = dgrp*4 .. dgrp*4+3
    int jbase = wave * 256;
    const float* vrow = qkv + ((size_t)b * SEQ + jbase + q) * QKV3
                      + 2 * DIM_HEAD + dgrp * 4;
    float acc[8][4] = {};
    #pragma unroll 4
    for (int jj = 0; jj < 64; ++jj) {
        float4 v = *(const float4*)(vrow + (size_t)jj * 4 * QKV3);
        int jw = jbase + 4 * jj + q;
        float pv[8];
        #pragma unroll
        for (int n = 0; n < 8; ++n) pv[n] = p_lds[n][jw];
        #pragma unroll
        for (int n = 0; n < 8; ++n) {
            acc[n][0] = fmaf(pv[n], v.x, acc[n][0]);
            acc[n][1] = fmaf(pv[n], v.y, acc[n][1]);
            acc[n][2] = fmaf(pv[n], v.z, acc[n][2]);
            acc[n][3] = fmaf(pv[n], v.w, acc[n][3]);
        }
    }

    // reduce across the 4 q-groups (lanes xor 16, 32)
    #pragma unroll
    for (int n = 0; n < 8; ++n)
        #pragma unroll
        for (int d = 0; d < 4; ++d) {
            acc[n][d] += __shfl_xor(acc[n][d], 16);
            acc[n][d] += __shfl_xor(acc[n][d], 32);
        }

    __syncthreads();   // all p reads done; safe to overlay ow on p_lds
    float (*ow)[8][64] = (float (*)[8][64])&p_lds[0][0];   // 8 KB overlay
    if (lane < 16) {
        #pragma unroll
        for (int n = 0; n < 8; ++n) {
            float4 o4 = { acc[n][0], acc[n][1], acc[n][2], acc[n][3] };
            *(float4*)&ow[wave][n][dgrp * 4] = o4;
        }
    }
    __syncthreads();

    // reduce across waves + head differences -> y[r][h*64+d]
    float* yr = y + (size_t)r * (HEADS * DIM_HEAD);
    #pragma unroll
    for (int s = 0; s < 2; ++s) {
        int c = t + 256 * s;
        int h = c >> 6, dd = c & 63;
        float oh = ow[0][h][dd] + ow[1][h][dd] + ow[2][h][dd] + ow[3][h][dd];
        float op = 0.0f;
        if (h) op = ow[0][h - 1][dd] + ow[1][h - 1][dd] + ow[2][h - 1][dd] + ow[3][h - 1][dd];
        yr[c] = oh - op;
    }
}

// ---------------------------------------------------------------------------
extern "C" void kernel_launch(void* const* d_in, const int* in_sizes, int n_in,
                              void* d_out, int out_size, void* d_ws, size_t ws_size,
                              hipStream_t stream)
{
    const float* x       = (const float*)d_in[0];
    const float* ln_g    = (const float*)d_in[1];
    const float* ln_b    = (const float*)d_in[2];
    const float* w_qkv   = (const float*)d_in[3];
    const float* w_out   = (const float*)d_in[4];
    const float* b_out   = (const float*)d_in[5];
    float* out = (float*)d_out;

    // ws: xn[ROWS*DIM] | qkv[ROWS*192] | dots[4M]   (~28.5 MB)
    float* xn   = (float*)d_ws;
    float* qkv  = xn + (size_t)ROWS * DIM;
    float* dots = qkv + (size_t)ROWS * QKV3;
    float* y    = xn;  // reuse (dead after qkv GEMM; rewritten by solve_pv)

    // 1) LayerNorm
    ln_kernel<<<ROWS, 256, 0, stream>>>(x, ln_g, ln_b, xn);

    // 2) qkv = xn @ w_qkv   [4096,512]x[512,192]   (64-tile kernel, N=192)
    gemm16_kernel<0><<<dim3(QKV3 / 64, ROWS / 64, 1), 256, 0, stream>>>(
        xn, w_qkv, qkv, nullptr,
        DIM, DIM, QKV3, QKV3, 0, 0, 0, 1.0f);

    // 3) dots[b] = 0.125 * q[b] @ k[b]^T   batched [1024,64]x[64,1024]  (128-tile)
    gemm16_big<1><<<dim3(SEQ / 128, SEQ / 128, Bsz), 512, 0, stream>>>(
        qkv, qkv + DIM_HEAD, dots, nullptr,
        DIM_HEAD, QKV3, QKV3, SEQ,
        (long)SEQ * QKV3, (long)SEQ * QKV3, (long)SEQ * SEQ, 0.125f);

    // 4) fused LML solve + PV + head differences -> y [4096, 512]
    solve_pv_kernel<<<ROWS, 256, 0, stream>>>(dots, qkv, y);

    // 5) out = y @ w_out + b_out   [4096,512]x[512,512]  (128-tile)
    gemm16_big<0><<<dim3(DIM / 128, ROWS / 128, 1), 512, 0, stream>>>(
        y, w_out, out, b_out,
        DIM, DIM, DIM, DIM, 0, 0, 0, 1.0f);
}

// Round 13
// 224.463 us; speedup vs baseline: 1.0033x; 1.0033x over previous
//
#include <hip/hip_runtime.h>
#include <hip/hip_bf16.h>

// Problem constants
#define Bsz 4
#define SEQ 1024
#define DIM 512
#define HEADS 8
#define DIM_HEAD 64
#define ROWS (Bsz * SEQ)        // 4096
#define QKV3 (3 * DIM_HEAD)     // 192

typedef _Float16 f16x4 __attribute__((ext_vector_type(4)));
typedef _Float16 f16x2 __attribute__((ext_vector_type(2)));
typedef float f32x4 __attribute__((ext_vector_type(4)));

// ---------------------------------------------------------------------------
// LayerNorm: one block per row of x [ROWS, 512]  (unchanged)
// ---------------------------------------------------------------------------
__global__ __launch_bounds__(256) void ln_kernel(
    const float* __restrict__ x, const float* __restrict__ g,
    const float* __restrict__ beta, float* __restrict__ xn)
{
    int r = blockIdx.x;
    int t = threadIdx.x;
    const float* xr = x + (size_t)r * DIM;
    float v0 = xr[t], v1 = xr[t + 256];
    float s = v0 + v1, ss = v0 * v0 + v1 * v1;
    #pragma unroll
    for (int off = 32; off; off >>= 1) {
        s  += __shfl_xor(s, off);
        ss += __shfl_xor(ss, off);
    }
    __shared__ float rs[4], rss[4];
    int wave = t >> 6, lane = t & 63;
    if (lane == 0) { rs[wave] = s; rss[wave] = ss; }
    __syncthreads();
    s  = rs[0] + rs[1] + rs[2] + rs[3];
    ss = rss[0] + rss[1] + rss[2] + rss[3];
    float mu  = s * (1.0f / DIM);
    float var = ss * (1.0f / DIM) - mu * mu;
    float rstd = rsqrtf(var + 1e-5f);
    float* out = xn + (size_t)r * DIM;
    out[t]       = (v0 - mu) * rstd * g[t]       + beta[t];
    out[t + 256] = (v1 - mu) * rstd * g[t + 256] + beta[t + 256];
}

// ---------------------------------------------------------------------------
// fp16-MFMA GEMM, 64x64 tile (round-7 proven) — used for qkv (N=192)
// ---------------------------------------------------------------------------
template <int TRANS_B>
__global__ __launch_bounds__(256) void gemm16_kernel(
    const float* __restrict__ A, const float* __restrict__ B,
    float* __restrict__ C, const float* __restrict__ bias,
    int K, int lda, int ldb, int ldc,
    long strideA, long strideB, long strideC, float alpha)
{
    int bz = blockIdx.z;
    A += (size_t)bz * strideA;
    B += (size_t)bz * strideB;
    C += (size_t)bz * strideC;

    __shared__ _Float16 As[64][36];
    __shared__ _Float16 Bs[64][36];

    int t = threadIdx.x;
    int block_m = blockIdx.y * 64;
    int block_n = blockIdx.x * 64;
    int wave = t >> 6, lane = t & 63;
    int wm = wave >> 1, wn = wave & 1;
    int lrow = lane & 15, g = lane >> 4;

    int sm = t & 63;
    int kc = t >> 6;

    f32x4 acc[2][2] = {};

    for (int k0 = 0; k0 < K; k0 += 32) {
        {
            const float4* pa = reinterpret_cast<const float4*>(
                A + (size_t)(block_m + sm) * lda + k0 + kc * 8);
            float4 a0 = pa[0], a1 = pa[1];
            f16x4 h0 = { (_Float16)a0.x, (_Float16)a0.y, (_Float16)a0.z, (_Float16)a0.w };
            f16x4 h1 = { (_Float16)a1.x, (_Float16)a1.y, (_Float16)a1.z, (_Float16)a1.w };
            *(f16x4*)&As[sm][kc * 8]     = h0;
            *(f16x4*)&As[sm][kc * 8 + 4] = h1;
        }
        if (TRANS_B) {
            const float4* pb = reinterpret_cast<const float4*>(
                B + (size_t)(block_n + sm) * ldb + k0 + kc * 8);
            float4 b0 = pb[0], b1 = pb[1];
            f16x4 h0 = { (_Float16)b0.x, (_Float16)b0.y, (_Float16)b0.z, (_Float16)b0.w };
            f16x4 h1 = { (_Float16)b1.x, (_Float16)b1.y, (_Float16)b1.z, (_Float16)b1.w };
            *(f16x4*)&Bs[sm][kc * 8]     = h0;
            *(f16x4*)&Bs[sm][kc * 8 + 4] = h1;
        } else {
            const float* pb = B + (size_t)(k0 + kc * 8) * ldb + block_n + sm;
            float b[8];
            #pragma unroll
            for (int i = 0; i < 8; ++i) b[i] = pb[(size_t)i * ldb];
            f16x4 h0 = { (_Float16)b[0], (_Float16)b[1], (_Float16)b[2], (_Float16)b[3] };
            f16x4 h1 = { (_Float16)b[4], (_Float16)b[5], (_Float16)b[6], (_Float16)b[7] };
            *(f16x4*)&Bs[sm][kc * 8]     = h0;
            *(f16x4*)&Bs[sm][kc * 8 + 4] = h1;
        }
        __syncthreads();
        #pragma unroll
        for (int ks = 0; ks < 2; ++ks) {
            f16x4 a0 = *(const f16x4*)&As[32 * wm + lrow][ks * 16 + g * 4];
            f16x4 a1 = *(const f16x4*)&As[32 * wm + 16 + lrow][ks * 16 + g * 4];
            f16x4 b0 = *(const f16x4*)&Bs[32 * wn + lrow][ks * 16 + g * 4];
            f16x4 b1 = *(const f16x4*)&Bs[32 * wn + 16 + lrow][ks * 16 + g * 4];
            acc[0][0] = __builtin_amdgcn_mfma_f32_16x16x16f16(a0, b0, acc[0][0], 0, 0, 0);
            acc[0][1] = __builtin_amdgcn_mfma_f32_16x16x16f16(a0, b1, acc[0][1], 0, 0, 0);
            acc[1][0] = __builtin_amdgcn_mfma_f32_16x16x16f16(a1, b0, acc[1][0], 0, 0, 0);
            acc[1][1] = __builtin_amdgcn_mfma_f32_16x16x16f16(a1, b1, acc[1][1], 0, 0, 0);
        }
        __syncthreads();
    }

    #pragma unroll
    for (int mt = 0; mt < 2; ++mt)
        #pragma unroll
        for (int nt = 0; nt < 2; ++nt) {
            int n = block_n + 32 * wn + 16 * nt + lrow;
            float bv = bias ? bias[n] : 0.0f;
            #pragma unroll
            for (int i = 0; i < 4; ++i) {
                int m = block_m + 32 * wm + 16 * mt + g * 4 + i;
                C[(size_t)m * ldc + n] = acc[mt][nt][i] * alpha + bv;
            }
        }
}

// ---------------------------------------------------------------------------
// fp16-MFMA GEMM, 128x128 tile, 512 threads (round-11; used for dots, out)
// ---------------------------------------------------------------------------
template <int TRANS_B>
__global__ __launch_bounds__(512) void gemm16_big(
    const float* __restrict__ A, const float* __restrict__ B,
    float* __restrict__ C, const float* __restrict__ bias,
    int K, int lda, int ldb, int ldc,
    long strideA, long strideB, long strideC, float alpha)
{
    int bz = blockIdx.z;
    A += (size_t)bz * strideA;
    B += (size_t)bz * strideB;
    C += (size_t)bz * strideC;

    __shared__ _Float16 As[128][36];   // 9 KB
    __shared__ _Float16 Bs[128][36];   // 9 KB

    int t = threadIdx.x;
    int block_m = blockIdx.y * 128;
    int block_n = blockIdx.x * 128;
    int wave = t >> 6, lane = t & 63;
    int wm = wave >> 2, wn = wave & 3;      // 2 x 4
    int lrow = lane & 15, g = lane >> 4;

    int sm = t & 127;   // staging row (m or n)
    int kc = t >> 7;    // 0..3: k-chunk of 8

    f32x4 acc[4][2] = {};

    for (int k0 = 0; k0 < K; k0 += 32) {
        {
            const float4* pa = reinterpret_cast<const float4*>(
                A + (size_t)(block_m + sm) * lda + k0 + kc * 8);
            float4 a0 = pa[0], a1 = pa[1];
            f16x4 h0 = { (_Float16)a0.x, (_Float16)a0.y, (_Float16)a0.z, (_Float16)a0.w };
            f16x4 h1 = { (_Float16)a1.x, (_Float16)a1.y, (_Float16)a1.z, (_Float16)a1.w };
            *(f16x4*)&As[sm][kc * 8]     = h0;
            *(f16x4*)&As[sm][kc * 8 + 4] = h1;
        }
        if (TRANS_B) {
            const float4* pb = reinterpret_cast<const float4*>(
                B + (size_t)(block_n + sm) * ldb + k0 + kc * 8);
            float4 b0 = pb[0], b1 = pb[1];
            f16x4 h0 = { (_Float16)b0.x, (_Float16)b0.y, (_Float16)b0.z, (_Float16)b0.w };
            f16x4 h1 = { (_Float16)b1.x, (_Float16)b1.y, (_Float16)b1.z, (_Float16)b1.w };
            *(f16x4*)&Bs[sm][kc * 8]     = h0;
            *(f16x4*)&Bs[sm][kc * 8 + 4] = h1;
        } else {
            const float* pb = B + (size_t)(k0 + kc * 8) * ldb + block_n + sm;
            float b[8];
            #pragma unroll
            for (int i = 0; i < 8; ++i) b[i] = pb[(size_t)i * ldb];
            f16x4 h0 = { (_Float16)b[0], (_Float16)b[1], (_Float16)b[2], (_Float16)b[3] };
            f16x4 h1 = { (_Float16)b[4], (_Float16)b[5], (_Float16)b[6], (_Float16)b[7] };
            *(f16x4*)&Bs[sm][kc * 8]     = h0;
            *(f16x4*)&Bs[sm][kc * 8 + 4] = h1;
        }
        __syncthreads();
        #pragma unroll
        for (int ks = 0; ks < 2; ++ks) {
            f16x4 a[4], bb[2];
            #pragma unroll
            for (int mt = 0; mt < 4; ++mt)
                a[mt] = *(const f16x4*)&As[64 * wm + 16 * mt + lrow][ks * 16 + g * 4];
            #pragma unroll
            for (int nt = 0; nt < 2; ++nt)
                bb[nt] = *(const f16x4*)&Bs[32 * wn + 16 * nt + lrow][ks * 16 + g * 4];
            #pragma unroll
            for (int mt = 0; mt < 4; ++mt)
                #pragma unroll
                for (int nt = 0; nt < 2; ++nt)
                    acc[mt][nt] = __builtin_amdgcn_mfma_f32_16x16x16f16(
                        a[mt], bb[nt], acc[mt][nt], 0, 0, 0);
        }
        __syncthreads();
    }

    #pragma unroll
    for (int mt = 0; mt < 4; ++mt)
        #pragma unroll
        for (int nt = 0; nt < 2; ++nt) {
            int n = block_n + 32 * wn + 16 * nt + lrow;
            float bv = bias ? bias[n] : 0.0f;
            #pragma unroll
            for (int i = 0; i < 4; ++i) {
                int m = block_m + 64 * wm + 16 * mt + g * 4 + i;
                C[(size_t)m * ldc + n] = acc[mt][nt][i] * alpha + bv;
            }
        }
}

// ---------------------------------------------------------------------------
// FUSED LML solve + PV.  Round-13 change: p stored as fp16 (16 KB LDS,
// was 32 KB) -> LDS occupancy cap 10 blocks/CU (was 5).  PV lane = (q2,
// dgrp): q2 = lane>>4 handles j-pair {2q2, 2q2+1} of each 8-j group; per
// iteration ONE f16x2 broadcast b32 read per head (8 total, consecutive
// dwords across q2 groups -> conflict-free) + 2 coalesced float4 V rows +
// 64 fma.  Solver math byte-identical to rounds 9-12 (series init + 4
// inclusive-guard Newton).  Accuracy: fp16 p adds ~2.5e-4 worst-case to
// absmax (analysis in round-13 notes) -- within the 6.7e-4 threshold.
// ---------------------------------------------------------------------------
__global__ __launch_bounds__(256) void solve_pv_kernel(
    const float* __restrict__ dots, const float* __restrict__ qkv,
    float* __restrict__ y)
{
    int r = blockIdx.x;
    int b = r >> 10;
    int t = threadIdx.x;
    int wave = t >> 6, lane = t & 63;
    int nbase = wave * 2;            // this wave solves N = nbase+1, nbase+2

    __shared__ _Float16 p16[8][1024];  // 16 KB; first 8 KB reused as ow later

    const float* x = dots + (size_t)r * SEQ;

    float e[16];
    #pragma unroll
    for (int s = 0; s < 4; ++s) {
        float4 v = *(const float4*)(x + lane * 4 + 256 * s);
        e[4 * s + 0] = v.x; e[4 * s + 1] = v.y;
        e[4 * s + 2] = v.z; e[4 * s + 3] = v.w;
    }
    float mx = e[0], mn = e[0];
    #pragma unroll
    for (int s = 1; s < 16; ++s) { mx = fmaxf(mx, e[s]); mn = fminf(mn, e[s]); }
    #pragma unroll
    for (int off = 32; off; off >>= 1) {
        mx = fmaxf(mx, __shfl_xor(mx, off));
        mn = fminf(mn, __shfl_xor(mn, off));
    }
    #pragma unroll
    for (int s = 0; s < 16; ++s) e[s] = __expf(e[s]);

    // E1..E4 = sums of e^x, e^2x, e^3x, e^4x (for the series init)
    float E1 = 0, E2 = 0, E3 = 0, E4 = 0;
    #pragma unroll
    for (int s = 0; s < 16; ++s) {
        float u = e[s], u2 = u * u;
        E1 += u; E2 += u2; E3 += u2 * u; E4 += u2 * u2;
    }
    #pragma unroll
    for (int off = 32; off; off >>= 1) {
        E1 += __shfl_xor(E1, off); E2 += __shfl_xor(E2, off);
        E3 += __shfl_xor(E3, off); E4 += __shfl_xor(E4, off);
    }

    float lo[2], hi[2], Nf[2], nu[2];
    #pragma unroll
    for (int k = 0; k < 2; ++k) {
        int N = nbase + k + 1;
        Nf[k] = (float)N;
        float lgt = __logf((float)N / (float)(SEQ - N));
        lo[k] = lgt - mx;             // provable bracket
        hi[k] = lgt - mn;
        // scalar Newton on the quartic series in t = e^nu
        float t0 = Nf[k] * __builtin_amdgcn_rcpf(E1);
        float tt = t0;
        #pragma unroll
        for (int it = 0; it < 4; ++it) {
            float gg = tt * (E1 + tt * (-E2 + tt * (E3 - tt * E4))) - Nf[k];
            float gp = E1 + tt * (-2.0f * E2 + tt * (3.0f * E3 - 4.0f * E4 * tt));
            float tn = tt - gg * __builtin_amdgcn_rcpf(gp);
            tt = (tn > 0.0f && tn < 1.0f) ? tn : t0;
        }
        float v = __logf(tt);
        nu[k] = (v > lo[k] && v < hi[k]) ? v : 0.5f * (lo[k] + hi[k]);
    }

    // ---- 4 bracket-guarded full Newton evals (inclusive-bound guard) ----
    for (int it = 0; it < 4; ++it) {
        float S[2], Sp[2];
        #pragma unroll
        for (int k = 0; k < 2; ++k) {
            float tn = __expf(nu[k]);
            float sn = 0.0f, spn = 0.0f;
            #pragma unroll
            for (int s = 0; s < 8; ++s) {
                float u1 = e[2 * s] * tn, u2 = e[2 * s + 1] * tn;
                float a1 = 1.0f + u1, a2 = 1.0f + u2;
                float rr = __builtin_amdgcn_rcpf(a1 * a2);
                float inv1 = rr * a2, inv2 = rr * a1;     // = 1/a1, 1/a2
                float p1 = u1 * inv1, p2 = u2 * inv2;
                sn += p1 + p2;
                spn = fmaf(p1, inv1, spn);                // p(1-p) = p*inv
                spn = fmaf(p2, inv2, spn);
            }
            S[k] = sn; Sp[k] = spn;
        }
        #pragma unroll
        for (int k = 0; k < 2; ++k) {
            #pragma unroll
            for (int off = 32; off; off >>= 1) {
                S[k]  += __shfl_xor(S[k], off);
                Sp[k] += __shfl_xor(Sp[k], off);
            }
            if (S[k] < Nf[k]) lo[k] = nu[k]; else hi[k] = nu[k];
            float step = (Nf[k] - S[k]) * __builtin_amdgcn_rcpf(Sp[k]);
            float cand = nu[k] + step;
            if (!(cand >= lo[k] && cand <= hi[k])) cand = 0.5f * (lo[k] + hi[k]);
            nu[k] = cand;
        }
    }

    // ---- write p (fp16) for this wave's 2 nus from register e[] ----
    #pragma unroll
    for (int k = 0; k < 2; ++k) {
        float tn = __expf(nu[k]);
        #pragma unroll
        for (int s = 0; s < 4; ++s) {
            float u0 = e[4 * s + 0] * tn, u1 = e[4 * s + 1] * tn;
            float u2 = e[4 * s + 2] * tn, u3 = e[4 * s + 3] * tn;
            float p0 = u0 * __builtin_amdgcn_rcpf(1.0f + u0);
            float p1 = u1 * __builtin_amdgcn_rcpf(1.0f + u1);
            float p2 = u2 * __builtin_amdgcn_rcpf(1.0f + u2);
            float p3 = u3 * __builtin_amdgcn_rcpf(1.0f + u3);
            f16x4 hp = { (_Float16)p0, (_Float16)p1, (_Float16)p2, (_Float16)p3 };
            *(f16x4*)&p16[nbase + k][lane * 4 + 256 * s] = hp;
        }
    }
    __syncthreads();

    // ---- PV: wave w covers j in [256w, 256w+256); lane = (q2, dgrp) ----
    int q2 = lane >> 4;          // j-pair = jbase + 8*jj + 2*q2 + {0,1}
    int dgrp = lane & 15;        // d = dgrp*4 .. dgrp*4+3
    int jbase = wave * 256;
    const float* vrow0 = qkv + ((size_t)b * SEQ + jbase + 2 * q2) * QKV3
                       + 2 * DIM_HEAD + dgrp * 4;
    float acc[8][4] = {};
    #pragma unroll 4
    for (int jj = 0; jj < 32; ++jj) {
        const float* vr = vrow0 + (size_t)jj * 8 * QKV3;
        float4 va = *(const float4*)vr;
        float4 vb = *(const float4*)(vr + QKV3);
        int j0 = jbase + 8 * jj + 2 * q2;
        float pa[8], pb[8];
        #pragma unroll
        for (int n = 0; n < 8; ++n) {
            f16x2 ph = *(const f16x2*)&p16[n][j0];
            pa[n] = (float)ph[0];
            pb[n] = (float)ph[1];
        }
        #pragma unroll
        for (int n = 0; n < 8; ++n) {
            acc[n][0] = fmaf(pa[n], va.x, acc[n][0]);
            acc[n][1] = fmaf(pa[n], va.y, acc[n][1]);
            acc[n][2] = fmaf(pa[n], va.z, acc[n][2]);
            acc[n][3] = fmaf(pa[n], va.w, acc[n][3]);
            acc[n][0] = fmaf(pb[n], vb.x, acc[n][0]);
            acc[n][1] = fmaf(pb[n], vb.y, acc[n][1]);
            acc[n][2] = fmaf(pb[n], vb.z, acc[n][2]);
            acc[n][3] = fmaf(pb[n], vb.w, acc[n][3]);
        }
    }

    // reduce across the 4 q2-groups (lanes xor 16, 32)
    #pragma unroll
    for (int n = 0; n < 8; ++n)
        #pragma unroll
        for (int d = 0; d < 4; ++d) {
            acc[n][d] += __shfl_xor(acc[n][d], 16);
            acc[n][d] += __shfl_xor(acc[n][d], 32);
        }

    __syncthreads();   // all p reads done; safe to overlay ow on p16
    float (*ow)[8][64] = (float (*)[8][64])&p16[0][0];   // 8 KB overlay
    if (lane < 16) {
        #pragma unroll
        for (int n = 0; n < 8; ++n) {
            float4 o4 = { acc[n][0], acc[n][1], acc[n][2], acc[n][3] };
            *(float4*)&ow[wave][n][dgrp * 4] = o4;
        }
    }
    __syncthreads();

    // reduce across waves + head differences -> y[r][h*64+d]
    float* yr = y + (size_t)r * (HEADS * DIM_HEAD);
    #pragma unroll
    for (int s = 0; s < 2; ++s) {
        int c = t + 256 * s;
        int h = c >> 6, dd = c & 63;
        float oh = ow[0][h][dd] + ow[1][h][dd] + ow[2][h][dd] + ow[3][h][dd];
        float op = 0.0f;
        if (h) op = ow[0][h - 1][dd] + ow[1][h - 1][dd] + ow[2][h - 1][dd] + ow[3][h - 1][dd];
        yr[c] = oh - op;
    }
}

// ---------------------------------------------------------------------------
extern "C" void kernel_launch(void* const* d_in, const int* in_sizes, int n_in,
                              void* d_out, int out_size, void* d_ws, size_t ws_size,
                              hipStream_t stream)
{
    const float* x       = (const float*)d_in[0];
    const float* ln_g    = (const float*)d_in[1];
    const float* ln_b    = (const float*)d_in[2];
    const float* w_qkv   = (const float*)d_in[3];
    const float* w_out   = (const float*)d_in[4];
    const float* b_out   = (const float*)d_in[5];
    float* out = (float*)d_out;

    // ws: xn[ROWS*DIM] | qkv[ROWS*192] | dots[4M]   (~28.5 MB)
    float* xn   = (float*)d_ws;
    float* qkv  = xn + (size_t)ROWS * DIM;
    float* dots = qkv + (size_t)ROWS * QKV3;
    float* y    = xn;  // reuse (dead after qkv GEMM; rewritten by solve_pv)

    // 1) LayerNorm
    ln_kernel<<<ROWS, 256, 0, stream>>>(x, ln_g, ln_b, xn);

    // 2) qkv = xn @ w_qkv   [4096,512]x[512,192]   (64-tile kernel, N=192)
    gemm16_kernel<0><<<dim3(QKV3 / 64, ROWS / 64, 1), 256, 0, stream>>>(
        xn, w_qkv, qkv, nullptr,
        DIM, DIM, QKV3, QKV3, 0, 0, 0, 1.0f);

    // 3) dots[b] = 0.125 * q[b] @ k[b]^T   batched [1024,64]x[64,1024]  (128-tile)
    gemm16_big<1><<<dim3(SEQ / 128, SEQ / 128, Bsz), 512, 0, stream>>>(
        qkv, qkv + DIM_HEAD, dots, nullptr,
        DIM_HEAD, QKV3, QKV3, SEQ,
        (long)SEQ * QKV3, (long)SEQ * QKV3, (long)SEQ * SEQ, 0.125f);

    // 4) fused LML solve + PV + head differences -> y [4096, 512]
    solve_pv_kernel<<<ROWS, 256, 0, stream>>>(dots, qkv, y);

    // 5) out = y @ w_out + b_out   [4096,512]x[512,512]  (128-tile)
    gemm16_big<0><<<dim3(DIM / 128, ROWS / 128, 1), 512, 0, stream>>>(
        y, w_out, out, b_out,
        DIM, DIM, DIM, DIM, 0, 0, 0, 1.0f);
}

// Round 14
// 204.372 us; speedup vs baseline: 1.1020x; 1.0983x over previous
//
#include <hip/hip_runtime.h>
#include <hip/hip_bf16.h>

// Problem constants
#define Bsz 4
#define SEQ 1024
#define DIM 512
#define HEADS 8
#define DIM_HEAD 64
#define ROWS (Bsz * SEQ)        // 4096
#define QKV3 (3 * DIM_HEAD)     // 192

typedef _Float16 f16x4 __attribute__((ext_vector_type(4)));
typedef float f32x4 __attribute__((ext_vector_type(4)));

// ---------------------------------------------------------------------------
// LayerNorm: one block per row of x [ROWS, 512]  (unchanged)
// ---------------------------------------------------------------------------
__global__ __launch_bounds__(256) void ln_kernel(
    const float* __restrict__ x, const float* __restrict__ g,
    const float* __restrict__ beta, float* __restrict__ xn)
{
    int r = blockIdx.x;
    int t = threadIdx.x;
    const float* xr = x + (size_t)r * DIM;
    float v0 = xr[t], v1 = xr[t + 256];
    float s = v0 + v1, ss = v0 * v0 + v1 * v1;
    #pragma unroll
    for (int off = 32; off; off >>= 1) {
        s  += __shfl_xor(s, off);
        ss += __shfl_xor(ss, off);
    }
    __shared__ float rs[4], rss[4];
    int wave = t >> 6, lane = t & 63;
    if (lane == 0) { rs[wave] = s; rss[wave] = ss; }
    __syncthreads();
    s  = rs[0] + rs[1] + rs[2] + rs[3];
    ss = rss[0] + rss[1] + rss[2] + rss[3];
    float mu  = s * (1.0f / DIM);
    float var = ss * (1.0f / DIM) - mu * mu;
    float rstd = rsqrtf(var + 1e-5f);
    float* out = xn + (size_t)r * DIM;
    out[t]       = (v0 - mu) * rstd * g[t]       + beta[t];
    out[t + 256] = (v1 - mu) * rstd * g[t + 256] + beta[t + 256];
}

// ---------------------------------------------------------------------------
// fp16-MFMA GEMM, 64x64 tile (round-7 proven) — used for qkv (N=192)
// ---------------------------------------------------------------------------
template <int TRANS_B>
__global__ __launch_bounds__(256) void gemm16_kernel(
    const float* __restrict__ A, const float* __restrict__ B,
    float* __restrict__ C, const float* __restrict__ bias,
    int K, int lda, int ldb, int ldc,
    long strideA, long strideB, long strideC, float alpha)
{
    int bz = blockIdx.z;
    A += (size_t)bz * strideA;
    B += (size_t)bz * strideB;
    C += (size_t)bz * strideC;

    __shared__ _Float16 As[64][36];
    __shared__ _Float16 Bs[64][36];

    int t = threadIdx.x;
    int block_m = blockIdx.y * 64;
    int block_n = blockIdx.x * 64;
    int wave = t >> 6, lane = t & 63;
    int wm = wave >> 1, wn = wave & 1;
    int lrow = lane & 15, g = lane >> 4;

    int sm = t & 63;
    int kc = t >> 6;

    f32x4 acc[2][2] = {};

    for (int k0 = 0; k0 < K; k0 += 32) {
        {
            const float4* pa = reinterpret_cast<const float4*>(
                A + (size_t)(block_m + sm) * lda + k0 + kc * 8);
            float4 a0 = pa[0], a1 = pa[1];
            f16x4 h0 = { (_Float16)a0.x, (_Float16)a0.y, (_Float16)a0.z, (_Float16)a0.w };
            f16x4 h1 = { (_Float16)a1.x, (_Float16)a1.y, (_Float16)a1.z, (_Float16)a1.w };
            *(f16x4*)&As[sm][kc * 8]     = h0;
            *(f16x4*)&As[sm][kc * 8 + 4] = h1;
        }
        if (TRANS_B) {
            const float4* pb = reinterpret_cast<const float4*>(
                B + (size_t)(block_n + sm) * ldb + k0 + kc * 8);
            float4 b0 = pb[0], b1 = pb[1];
            f16x4 h0 = { (_Float16)b0.x, (_Float16)b0.y, (_Float16)b0.z, (_Float16)b0.w };
            f16x4 h1 = { (_Float16)b1.x, (_Float16)b1.y, (_Float16)b1.z, (_Float16)b1.w };
            *(f16x4*)&Bs[sm][kc * 8]     = h0;
            *(f16x4*)&Bs[sm][kc * 8 + 4] = h1;
        } else {
            const float* pb = B + (size_t)(k0 + kc * 8) * ldb + block_n + sm;
            float b[8];
            #pragma unroll
            for (int i = 0; i < 8; ++i) b[i] = pb[(size_t)i * ldb];
            f16x4 h0 = { (_Float16)b[0], (_Float16)b[1], (_Float16)b[2], (_Float16)b[3] };
            f16x4 h1 = { (_Float16)b[4], (_Float16)b[5], (_Float16)b[6], (_Float16)b[7] };
            *(f16x4*)&Bs[sm][kc * 8]     = h0;
            *(f16x4*)&Bs[sm][kc * 8 + 4] = h1;
        }
        __syncthreads();
        #pragma unroll
        for (int ks = 0; ks < 2; ++ks) {
            f16x4 a0 = *(const f16x4*)&As[32 * wm + lrow][ks * 16 + g * 4];
            f16x4 a1 = *(const f16x4*)&As[32 * wm + 16 + lrow][ks * 16 + g * 4];
            f16x4 b0 = *(const f16x4*)&Bs[32 * wn + lrow][ks * 16 + g * 4];
            f16x4 b1 = *(const f16x4*)&Bs[32 * wn + 16 + lrow][ks * 16 + g * 4];
            acc[0][0] = __builtin_amdgcn_mfma_f32_16x16x16f16(a0, b0, acc[0][0], 0, 0, 0);
            acc[0][1] = __builtin_amdgcn_mfma_f32_16x16x16f16(a0, b1, acc[0][1], 0, 0, 0);
            acc[1][0] = __builtin_amdgcn_mfma_f32_16x16x16f16(a1, b0, acc[1][0], 0, 0, 0);
            acc[1][1] = __builtin_amdgcn_mfma_f32_16x16x16f16(a1, b1, acc[1][1], 0, 0, 0);
        }
        __syncthreads();
    }

    #pragma unroll
    for (int mt = 0; mt < 2; ++mt)
        #pragma unroll
        for (int nt = 0; nt < 2; ++nt) {
            int n = block_n + 32 * wn + 16 * nt + lrow;
            float bv = bias ? bias[n] : 0.0f;
            #pragma unroll
            for (int i = 0; i < 4; ++i) {
                int m = block_m + 32 * wm + 16 * mt + g * 4 + i;
                C[(size_t)m * ldc + n] = acc[mt][nt][i] * alpha + bv;
            }
        }
}

// ---------------------------------------------------------------------------
// fp16-MFMA GEMM, 128x128 tile, 512 threads (round-11; used for dots, out)
// ---------------------------------------------------------------------------
template <int TRANS_B>
__global__ __launch_bounds__(512) void gemm16_big(
    const float* __restrict__ A, const float* __restrict__ B,
    float* __restrict__ C, const float* __restrict__ bias,
    int K, int lda, int ldb, int ldc,
    long strideA, long strideB, long strideC, float alpha)
{
    int bz = blockIdx.z;
    A += (size_t)bz * strideA;
    B += (size_t)bz * strideB;
    C += (size_t)bz * strideC;

    __shared__ _Float16 As[128][36];   // 9 KB
    __shared__ _Float16 Bs[128][36];   // 9 KB

    int t = threadIdx.x;
    int block_m = blockIdx.y * 128;
    int block_n = blockIdx.x * 128;
    int wave = t >> 6, lane = t & 63;
    int wm = wave >> 2, wn = wave & 3;      // 2 x 4
    int lrow = lane & 15, g = lane >> 4;

    int sm = t & 127;   // staging row (m or n)
    int kc = t >> 7;    // 0..3: k-chunk of 8

    f32x4 acc[4][2] = {};

    for (int k0 = 0; k0 < K; k0 += 32) {
        {
            const float4* pa = reinterpret_cast<const float4*>(
                A + (size_t)(block_m + sm) * lda + k0 + kc * 8);
            float4 a0 = pa[0], a1 = pa[1];
            f16x4 h0 = { (_Float16)a0.x, (_Float16)a0.y, (_Float16)a0.z, (_Float16)a0.w };
            f16x4 h1 = { (_Float16)a1.x, (_Float16)a1.y, (_Float16)a1.z, (_Float16)a1.w };
            *(f16x4*)&As[sm][kc * 8]     = h0;
            *(f16x4*)&As[sm][kc * 8 + 4] = h1;
        }
        if (TRANS_B) {
            const float4* pb = reinterpret_cast<const float4*>(
                B + (size_t)(block_n + sm) * ldb + k0 + kc * 8);
            float4 b0 = pb[0], b1 = pb[1];
            f16x4 h0 = { (_Float16)b0.x, (_Float16)b0.y, (_Float16)b0.z, (_Float16)b0.w };
            f16x4 h1 = { (_Float16)b1.x, (_Float16)b1.y, (_Float16)b1.z, (_Float16)b1.w };
            *(f16x4*)&Bs[sm][kc * 8]     = h0;
            *(f16x4*)&Bs[sm][kc * 8 + 4] = h1;
        } else {
            const float* pb = B + (size_t)(k0 + kc * 8) * ldb + block_n + sm;
            float b[8];
            #pragma unroll
            for (int i = 0; i < 8; ++i) b[i] = pb[(size_t)i * ldb];
            f16x4 h0 = { (_Float16)b[0], (_Float16)b[1], (_Float16)b[2], (_Float16)b[3] };
            f16x4 h1 = { (_Float16)b[4], (_Float16)b[5], (_Float16)b[6], (_Float16)b[7] };
            *(f16x4*)&Bs[sm][kc * 8]     = h0;
            *(f16x4*)&Bs[sm][kc * 8 + 4] = h1;
        }
        __syncthreads();
        #pragma unroll
        for (int ks = 0; ks < 2; ++ks) {
            f16x4 a[4], bb[2];
            #pragma unroll
            for (int mt = 0; mt < 4; ++mt)
                a[mt] = *(const f16x4*)&As[64 * wm + 16 * mt + lrow][ks * 16 + g * 4];
            #pragma unroll
            for (int nt = 0; nt < 2; ++nt)
                bb[nt] = *(const f16x4*)&Bs[32 * wn + 16 * nt + lrow][ks * 16 + g * 4];
            #pragma unroll
            for (int mt = 0; mt < 4; ++mt)
                #pragma unroll
                for (int nt = 0; nt < 2; ++nt)
                    acc[mt][nt] = __builtin_amdgcn_mfma_f32_16x16x16f16(
                        a[mt], bb[nt], acc[mt][nt], 0, 0, 0);
        }
        __syncthreads();
    }

    #pragma unroll
    for (int mt = 0; mt < 4; ++mt)
        #pragma unroll
        for (int nt = 0; nt < 2; ++nt) {
            int n = block_n + 32 * wn + 16 * nt + lrow;
            float bv = bias ? bias[n] : 0.0f;
            #pragma unroll
            for (int i = 0; i < 4; ++i) {
                int m = block_m + 64 * wm + 16 * mt + g * 4 + i;
                C[(size_t)m * ldc + n] = acc[mt][nt][i] * alpha + bv;
            }
        }
}

// ---------------------------------------------------------------------------
// FUSED LML solve + MFMA PV.  Round-14: TWO rows per block.
// Solve: wave w handles row r0+(w>>1), nus N = (w&1)*4+1 .. +4 (round-6
// proven 4-nu/wave config; round-9 proven series init + 4 inclusive-guard
// Newton evals; arithmetic unchanged).
// p written as fp16 into pA[16][1032]: m = i*8+n (i=row-in-block, n=head).
// PV: O[m][d] = sum_j pA[m][j] * V[j][d]  == MFMA GEMM M=16,N=64,K=1024.
// V staged per 32-k tile via gemm16's proven TRANS_B=0 staging (Bs[64][36],
// 8 coalesced scalar loads/thread, f16 convert).  Wave w owns d-cols
// [16w,16w+16): 64 MFMA/wave total replaces ~2560 VALU insts/lane.
// ---------------------------------------------------------------------------
__global__ __launch_bounds__(256) void solve_pv_kernel(
    const float* __restrict__ dots, const float* __restrict__ qkv,
    float* __restrict__ y)
{
    int r0 = blockIdx.x * 2;
    int b = r0 >> 10;
    int t = threadIdx.x;
    int wave = t >> 6, lane = t & 63;
    int row = r0 + (wave >> 1);
    int nbase = (wave & 1) * 4;      // this wave solves N = nbase+1 .. nbase+4

    __shared__ _Float16 pA[16][1032];     // 33 KB  A-operand (p, fp16)
    __shared__ _Float16 Bs[2][64][36];    // 9.2 KB V^T staging tiles
    __shared__ float    ow[16][65];       // 4.2 KB O output

    const float* x = dots + (size_t)row * SEQ;

    float e[16];
    #pragma unroll
    for (int s = 0; s < 4; ++s) {
        float4 v = *(const float4*)(x + lane * 4 + 256 * s);
        e[4 * s + 0] = v.x; e[4 * s + 1] = v.y;
        e[4 * s + 2] = v.z; e[4 * s + 3] = v.w;
    }
    float mx = e[0], mn = e[0];
    #pragma unroll
    for (int s = 1; s < 16; ++s) { mx = fmaxf(mx, e[s]); mn = fminf(mn, e[s]); }
    #pragma unroll
    for (int off = 32; off; off >>= 1) {
        mx = fmaxf(mx, __shfl_xor(mx, off));
        mn = fminf(mn, __shfl_xor(mn, off));
    }
    #pragma unroll
    for (int s = 0; s < 16; ++s) e[s] = __expf(e[s]);

    // E1..E4 for the series init
    float E1 = 0, E2 = 0, E3 = 0, E4 = 0;
    #pragma unroll
    for (int s = 0; s < 16; ++s) {
        float u = e[s], u2 = u * u;
        E1 += u; E2 += u2; E3 += u2 * u; E4 += u2 * u2;
    }
    #pragma unroll
    for (int off = 32; off; off >>= 1) {
        E1 += __shfl_xor(E1, off); E2 += __shfl_xor(E2, off);
        E3 += __shfl_xor(E3, off); E4 += __shfl_xor(E4, off);
    }

    float lo[4], hi[4], Nf[4], nu[4];
    #pragma unroll
    for (int k = 0; k < 4; ++k) {
        int N = nbase + k + 1;
        Nf[k] = (float)N;
        float lgt = __logf((float)N / (float)(SEQ - N));
        lo[k] = lgt - mx;             // provable bracket
        hi[k] = lgt - mn;
        float t0 = Nf[k] * __builtin_amdgcn_rcpf(E1);
        float tt = t0;
        #pragma unroll
        for (int it = 0; it < 4; ++it) {
            float gg = tt * (E1 + tt * (-E2 + tt * (E3 - tt * E4))) - Nf[k];
            float gp = E1 + tt * (-2.0f * E2 + tt * (3.0f * E3 - 4.0f * E4 * tt));
            float tn = tt - gg * __builtin_amdgcn_rcpf(gp);
            tt = (tn > 0.0f && tn < 1.0f) ? tn : t0;
        }
        float v = __logf(tt);
        nu[k] = (v > lo[k] && v < hi[k]) ? v : 0.5f * (lo[k] + hi[k]);
    }

    // ---- 4 bracket-guarded full Newton evals (inclusive-bound guard) ----
    for (int it = 0; it < 4; ++it) {
        float S[4], Sp[4];
        #pragma unroll
        for (int k = 0; k < 4; ++k) {
            float tn = __expf(nu[k]);
            float sn = 0.0f, spn = 0.0f;
            #pragma unroll
            for (int s = 0; s < 8; ++s) {
                float u1 = e[2 * s] * tn, u2 = e[2 * s + 1] * tn;
                float a1 = 1.0f + u1, a2 = 1.0f + u2;
                float rr = __builtin_amdgcn_rcpf(a1 * a2);
                float inv1 = rr * a2, inv2 = rr * a1;     // = 1/a1, 1/a2
                float p1 = u1 * inv1, p2 = u2 * inv2;
                sn += p1 + p2;
                spn = fmaf(p1, inv1, spn);                // p(1-p) = p*inv
                spn = fmaf(p2, inv2, spn);
            }
            S[k] = sn; Sp[k] = spn;
        }
        #pragma unroll
        for (int k = 0; k < 4; ++k) {
            #pragma unroll
            for (int off = 32; off; off >>= 1) {
                S[k]  += __shfl_xor(S[k], off);
                Sp[k] += __shfl_xor(Sp[k], off);
            }
            if (S[k] < Nf[k]) lo[k] = nu[k]; else hi[k] = nu[k];
            float step = (Nf[k] - S[k]) * __builtin_amdgcn_rcpf(Sp[k]);
            float cand = nu[k] + step;
            if (!(cand >= lo[k] && cand <= hi[k])) cand = 0.5f * (lo[k] + hi[k]);
            nu[k] = cand;
        }
    }

    // ---- write p (fp16) for this wave's 4 nus: row m = (w>>1)*8+nbase+k ----
    #pragma unroll
    for (int k = 0; k < 4; ++k) {
        int m = (wave >> 1) * 8 + nbase + k;
        float tn = __expf(nu[k]);
        #pragma unroll
        for (int s = 0; s < 4; ++s) {
            float u0 = e[4 * s + 0] * tn, u1 = e[4 * s + 1] * tn;
            float u2 = e[4 * s + 2] * tn, u3 = e[4 * s + 3] * tn;
            float p0 = u0 * __builtin_amdgcn_rcpf(1.0f + u0);
            float p1 = u1 * __builtin_amdgcn_rcpf(1.0f + u1);
            float p2 = u2 * __builtin_amdgcn_rcpf(1.0f + u2);
            float p3 = u3 * __builtin_amdgcn_rcpf(1.0f + u3);
            f16x4 hp = { (_Float16)p0, (_Float16)p1, (_Float16)p2, (_Float16)p3 };
            *(f16x4*)&pA[m][lane * 4 + 256 * s] = hp;
        }
    }
    __syncthreads();

    // ---- PV via MFMA: wave w owns d-cols [16w, 16w+16) ----
    int lrow = lane & 15, g = lane >> 4;
    int sd = t & 63;      // staging d
    int kc = t >> 6;      // staging k-chunk of 8
    const float* vbase = qkv + ((size_t)b * SEQ) * QKV3 + 2 * DIM_HEAD;

    f32x4 acc = {};
    for (int k0 = 0; k0 < SEQ; k0 += 64) {
        #pragma unroll
        for (int bufi = 0; bufi < 2; ++bufi) {
            const float* pb = vbase + (size_t)(k0 + bufi * 32 + kc * 8) * QKV3 + sd;
            float bv[8];
            #pragma unroll
            for (int i = 0; i < 8; ++i) bv[i] = pb[(size_t)i * QKV3];
            f16x4 h0 = { (_Float16)bv[0], (_Float16)bv[1], (_Float16)bv[2], (_Float16)bv[3] };
            f16x4 h1 = { (_Float16)bv[4], (_Float16)bv[5], (_Float16)bv[6], (_Float16)bv[7] };
            *(f16x4*)&Bs[bufi][sd][kc * 8]     = h0;
            *(f16x4*)&Bs[bufi][sd][kc * 8 + 4] = h1;
        }
        __syncthreads();
        #pragma unroll
        for (int bufi = 0; bufi < 2; ++bufi)
            #pragma unroll
            for (int ks = 0; ks < 2; ++ks) {
                f16x4 a  = *(const f16x4*)&pA[lrow][k0 + bufi * 32 + ks * 16 + g * 4];
                f16x4 bb = *(const f16x4*)&Bs[bufi][16 * wave + lrow][ks * 16 + g * 4];
                acc = __builtin_amdgcn_mfma_f32_16x16x16f16(a, bb, acc, 0, 0, 0);
            }
        __syncthreads();
    }

    // D[m = 4g+i][d = 16*wave + lrow]
    #pragma unroll
    for (int i = 0; i < 4; ++i) ow[4 * g + i][16 * wave + lrow] = acc[i];
    __syncthreads();

    // head differences -> y rows r0, r0+1 (1024 values)
    #pragma unroll
    for (int s = 0; s < 4; ++s) {
        int c = t + 256 * s;
        int i = c >> 9, col = c & 511;
        int n = col >> 6, d = col & 63;
        float oh = ow[i * 8 + n][d];
        float op = n ? ow[i * 8 + n - 1][d] : 0.0f;
        y[(size_t)(r0 + i) * (HEADS * DIM_HEAD) + col] = oh - op;
    }
}

// ---------------------------------------------------------------------------
extern "C" void kernel_launch(void* const* d_in, const int* in_sizes, int n_in,
                              void* d_out, int out_size, void* d_ws, size_t ws_size,
                              hipStream_t stream)
{
    const float* x       = (const float*)d_in[0];
    const float* ln_g    = (const float*)d_in[1];
    const float* ln_b    = (const float*)d_in[2];
    const float* w_qkv   = (const float*)d_in[3];
    const float* w_out   = (const float*)d_in[4];
    const float* b_out   = (const float*)d_in[5];
    float* out = (float*)d_out;

    // ws: xn[ROWS*DIM] | qkv[ROWS*192] | dots[4M]   (~28.5 MB)
    float* xn   = (float*)d_ws;
    float* qkv  = xn + (size_t)ROWS * DIM;
    float* dots = qkv + (size_t)ROWS * QKV3;
    float* y    = xn;  // reuse (dead after qkv GEMM; rewritten by solve_pv)

    // 1) LayerNorm
    ln_kernel<<<ROWS, 256, 0, stream>>>(x, ln_g, ln_b, xn);

    // 2) qkv = xn @ w_qkv   [4096,512]x[512,192]   (64-tile kernel, N=192)
    gemm16_kernel<0><<<dim3(QKV3 / 64, ROWS / 64, 1), 256, 0, stream>>>(
        xn, w_qkv, qkv, nullptr,
        DIM, DIM, QKV3, QKV3, 0, 0, 0, 1.0f);

    // 3) dots[b] = 0.125 * q[b] @ k[b]^T   batched [1024,64]x[64,1024]  (128-tile)
    gemm16_big<1><<<dim3(SEQ / 128, SEQ / 128, Bsz), 512, 0, stream>>>(
        qkv, qkv + DIM_HEAD, dots, nullptr,
        DIM_HEAD, QKV3, QKV3, SEQ,
        (long)SEQ * QKV3, (long)SEQ * QKV3, (long)SEQ * SEQ, 0.125f);

    // 4) fused LML solve + MFMA PV + head differences -> y [4096, 512]
    //    2 rows per block
    solve_pv_kernel<<<ROWS / 2, 256, 0, stream>>>(dots, qkv, y);

    // 5) out = y @ w_out + b_out   [4096,512]x[512,512]  (128-tile)
    gemm16_big<0><<<dim3(DIM / 128, ROWS / 128, 1), 512, 0, stream>>>(
        y, w_out, out, b_out,
        DIM, DIM, DIM, DIM, 0, 0, 0, 1.0f);
}